// Round 10
// baseline (138.460 us; speedup 1.0000x reference)
//
#include <hip/hip_runtime.h>
#include <hip/hip_fp16.h>
#include <hip/hip_bf16.h>

#define NL 26
#define ND 128
#define NT 64
#define NB 8192
#define NIPB 32   // items per block

typedef __attribute__((ext_vector_type(8))) short bf16x8;
typedef __attribute__((ext_vector_type(4))) float f32x4;

__device__ __forceinline__ uint32_t pk_bf16(float lo, float hi) {
    uint32_t r;
    asm("v_cvt_pk_bf16_f32 %0, %1, %2" : "=v"(r) : "v"(lo), "v"(hi));
    return r;
}

// ---------------------------------------------------------------------------
// Producer/consumer fused kernel. Block = 512 thr (8 waves), 32 items,
// grid = 256 = exactly 1 block/CU (LDS 136 KB pins it; launch_bounds(512,2)
// caps VGPR at 256 so occupancy can't silently collapse like round 9).
//  Waves 1-7 (producers): emission GEMM slab-by-slab (slab = 16 t), items
//    split 5/5/5/5/4/4/4; exp(em)/16 fp16 -> emT[t][label][item]; per-item
//    gold-score chunk right after its tile; per-slab LDS ready-flag (count 7).
//  Wave 0 (consumer): two independent 16-item MFMA-DP chains (interleaved),
//    per slab as soon as its flag fires. DP hides under streaming.
// DP arithmetic identical to rounds 8/9.
// ---------------------------------------------------------------------------
__global__ __launch_bounds__(512, 2) void crf_fused(
    const float* __restrict__ X, const int* __restrict__ Y,
    const float* __restrict__ P, float* __restrict__ partials)
{
    __shared__ float TrS[NL * NL];                    // 2704 B
    __shared__ __half emT[NT][32][NIPB];              // 131072 B
    __shared__ alignas(16) uint32_t pScr[2][16][20];  // 2560 B
    __shared__ float goldS[NIPB];                     // 128 B
    __shared__ int ready[4];

    const int tid = threadIdx.x;
    if (tid < 4) ready[tid] = 0;
    if (tid < NIPB) goldS[tid] = 0.f;
    for (int k = tid; k < NL * NL; k += 512) TrS[k] = P[NL * ND + k];
    __syncthreads();

    const int warp = tid >> 6;   // 0..7
    const int lane = tid & 63;
    const int r16  = lane & 15;
    const int kq   = lane >> 4;
    const int item0 = blockIdx.x * NIPB;

    if (warp > 0) {
        // ================= producers (waves 1..7) =================
        bf16x8 Bf[2][4];
        #pragma unroll
        for (int h = 0; h < 2; ++h) {
            int n = r16 + 16 * h;
            #pragma unroll
            for (int kb = 0; kb < 4; ++kb) {
                float w[8];
                if (n < NL) {
                    const float4* wp = reinterpret_cast<const float4*>(P + n * ND + kb * 32 + kq * 8);
                    float4 w0 = wp[0], w1 = wp[1];
                    w[0]=w0.x; w[1]=w0.y; w[2]=w0.z; w[3]=w0.w;
                    w[4]=w1.x; w[5]=w1.y; w[6]=w1.z; w[7]=w1.w;
                } else {
                    #pragma unroll
                    for (int jj = 0; jj < 8; ++jj) w[jj] = 0.f;
                }
                union { uint32_t u[4]; bf16x8 v; } pk;
                pk.u[0] = pk_bf16(w[0], w[1]); pk.u[1] = pk_bf16(w[2], w[3]);
                pk.u[2] = pk_bf16(w[4], w[5]); pk.u[3] = pk_bf16(w[6], w[7]);
                Bf[h][kb] = pk.v;
            }
        }

        const float4* X4 = reinterpret_cast<const float4*>(X);
        const int ibeg = (warp <= 4) ? (warp - 1) * 5 : 20 + (warp - 5) * 4;
        const int cnt  = (warp <= 4) ? 5 : 4;

        auto tile_load = [&](int it, int s, float4 (*xa)[2]) {
            size_t row  = (size_t)(item0 + it) * NT + s * 16 + r16;
            size_t base = row * 32 + kq * 2;
            #pragma unroll
            for (int kb = 0; kb < 4; ++kb) {
                xa[kb][0] = X4[base + kb * 8];
                xa[kb][1] = X4[base + kb * 8 + 1];
            }
        };
        auto tile_comp = [&](int it, int s, float4 (*xa)[2]) {
            f32x4 acc0 = {0.f,0.f,0.f,0.f}, acc1 = {0.f,0.f,0.f,0.f};
            #pragma unroll
            for (int kb = 0; kb < 4; ++kb) {
                union { uint32_t u[4]; bf16x8 v; } A;
                A.u[0] = pk_bf16(xa[kb][0].x, xa[kb][0].y);
                A.u[1] = pk_bf16(xa[kb][0].z, xa[kb][0].w);
                A.u[2] = pk_bf16(xa[kb][1].x, xa[kb][1].y);
                A.u[3] = pk_bf16(xa[kb][1].z, xa[kb][1].w);
                acc0 = __builtin_amdgcn_mfma_f32_16x16x32_bf16(A.v, Bf[0][kb], acc0, 0, 0, 0);
                acc1 = __builtin_amdgcn_mfma_f32_16x16x32_bf16(A.v, Bf[1][kb], acc1, 0, 0, 0);
            }
            // D layout: col = lane&15 = label, row = kq*4+q = t-offset  [m89]
            #pragma unroll
            for (int q = 0; q < 4; ++q) {
                int t = s * 16 + kq * 4 + q;
                emT[t][r16][it]      = __float2half(__expf(acc0[q]) * 0.0625f);
                emT[t][r16 + 16][it] = __float2half(__expf(acc1[q]) * 0.0625f);
            }
        };
        auto gold_chunk = [&](int it, int s) {
            if (lane < 16) {
                const int* yrow = Y + (size_t)(item0 + it) * NT;
                int t = s * 16 + lane;
                int yt = yrow[t];
                float g = __logf(__half2float(emT[t][yt][it]));
                if (t < NT - 1) g += TrS[yt * NL + yrow[t + 1]];
                #pragma unroll
                for (int mk = 8; mk >= 1; mk >>= 1) g += __shfl_xor(g, mk);
                if (lane == 0) goldS[it] += g;
            }
        };

        float4 xaA[4][2], xaB[4][2];
        const int ntile = 4 * cnt;
        int s = 0, k = 0;
        tile_load(ibeg, 0, xaA);
        #pragma unroll 1
        for (int li = 0; li < ntile; ++li) {
            if (li + 1 < ntile) {
                int kn = k + 1, sn = s;
                if (kn == cnt) { kn = 0; sn = s + 1; }
                tile_load(ibeg + kn, sn, (li & 1) ? xaA : xaB);
            }
            tile_comp(ibeg + k, s, (li & 1) ? xaB : xaA);
            gold_chunk(ibeg + k, s);
            if (++k == cnt) {
                __threadfence_block();
                if (lane == 0) atomicAdd(&ready[s], 1);
                k = 0; ++s;
            }
        }
        return;
    }

    // ================= consumer (wave 0) =================
    // E fragments (B-operand), k-permuted: k-slot 2s -> label s, 2s+1 -> s+16
    bf16x8 Ef[2];
    #pragma unroll
    for (int h = 0; h < 2; ++h) {
        int n = r16 + 16 * h;
        union { uint32_t u[4]; bf16x8 v; } c;
        #pragma unroll
        for (int w = 0; w < 4; ++w) {
            int sl = kq * 4 + w;
            float lo = (n < NL) ? __expf(TrS[sl * NL + n]) : 0.f;
            float hi = (n < NL && sl + 16 < NL) ? __expf(TrS[(sl + 16) * NL + n]) : 0.f;
            c.u[w] = pk_bf16(lo, hi);
        }
        Ef[h] = c.v;
    }

    bf16x8 pf[2];
    float M[2][4] = {{0.f,0.f,0.f,0.f},{0.f,0.f,0.f,0.f}};
    float pn0[2][4], pn1[2][4];
    const f32x4 zacc = {0.f, 0.f, 0.f, 0.f};

    #pragma unroll 1
    for (int s = 0; s < 4; ++s) {
        volatile int* rp = (volatile int*)&ready[s];
        while (*rp < 7) __builtin_amdgcn_s_sleep(2);
        __threadfence_block();

        int t = s * 16;
        if (s == 0) {
            #pragma unroll
            for (int g = 0; g < 2; ++g) {
                union { uint32_t u[4]; bf16x8 v; } c;
                #pragma unroll
                for (int w = 0; w < 4; ++w) {
                    int sl = kq * 4 + w;
                    float lo = __half2float(emT[0][sl][g * 16 + r16]);
                    float hi = (sl + 16 < NL) ? __half2float(emT[0][sl + 16][g * 16 + r16]) : 0.f;
                    c.u[w] = pk_bf16(lo, hi);
                }
                pf[g] = c.v;
            }
            t = 1;
        }
        const int tend = s * 16 + 16;
        #pragma unroll 1
        for (; t < tend; ++t) {
            #pragma unroll
            for (int g = 0; g < 2; ++g) {
                f32x4 d0 = __builtin_amdgcn_mfma_f32_16x16x32_bf16(pf[g], Ef[0], zacc, 0, 0, 0);
                f32x4 d1 = __builtin_amdgcn_mfma_f32_16x16x32_bf16(pf[g], Ef[1], zacc, 0, 0, 0);
                const __half2* pe0p = reinterpret_cast<const __half2*>(&emT[t][r16][g * 16 + kq * 4]);
                const __half2* pe1p = reinterpret_cast<const __half2*>(&emT[t][r16 + 16][g * 16 + kq * 4]);
                __half2 pe0a = pe0p[0], pe0b = pe0p[1];
                __half2 pe1a = pe1p[0], pe1b = pe1p[1];
                pn0[g][0] = d0[0] * __low2float(pe0a);  pn0[g][1] = d0[1] * __high2float(pe0a);
                pn0[g][2] = d0[2] * __low2float(pe0b);  pn0[g][3] = d0[3] * __high2float(pe0b);
                pn1[g][0] = d1[0] * __low2float(pe1a);  pn1[g][1] = d1[1] * __high2float(pe1a);
                pn1[g][2] = d1[2] * __low2float(pe1b);  pn1[g][3] = d1[3] * __high2float(pe1b);

                if ((t & 3) == 0) {                    // renorm every 4 steps
                    #pragma unroll
                    for (int q = 0; q < 4; ++q) {
                        float m = fmaxf(pn0[g][q], pn1[g][q]);
                        m = fmaxf(m, __shfl_xor(m, 1));
                        m = fmaxf(m, __shfl_xor(m, 2));
                        m = fmaxf(m, __shfl_xor(m, 4));
                        m = fmaxf(m, __shfl_xor(m, 8));
                        float r = __builtin_amdgcn_rcpf(m);
                        pn0[g][q] *= r; pn1[g][q] *= r;
                        M[g][q] += __logf(m);
                    }
                }
                // repack to next A-frag via LDS transpose
                #pragma unroll
                for (int q = 0; q < 4; ++q)
                    pScr[g][kq * 4 + q][r16] = pk_bf16(pn0[g][q], pn1[g][q]);
                uint4 pw = *reinterpret_cast<const uint4*>(&pScr[g][r16][kq * 4]);
                union { uint4 u; bf16x8 v; } pc; pc.u = pw;
                pf[g] = pc.v;
            }
        }
    }

    // ---- epilogue: per-item logZ, combine with producer-written gold ----
    float tot = 0.f;
    #pragma unroll
    for (int g = 0; g < 2; ++g) {
        #pragma unroll
        for (int q = 0; q < 4; ++q) {
            float ssum = pn0[g][q] + pn1[g][q];
            ssum += __shfl_xor(ssum, 1);
            ssum += __shfl_xor(ssum, 2);
            ssum += __shfl_xor(ssum, 4);
            ssum += __shfl_xor(ssum, 8);
            float logZ = M[g][q] + __logf(ssum);
            tot += goldS[g * 16 + kq * 4 + q] - logZ;   // 1/16 scales cancel
        }
    }
    tot += __shfl_xor(tot, 16);
    tot += __shfl_xor(tot, 32);
    if (lane == 0) partials[blockIdx.x] = tot;
}

__global__ void crf_reduce2(const float* __restrict__ partials,
                            float* __restrict__ out, int n) {
    __shared__ float red[256];
    float s = 0.f;
    for (int i = threadIdx.x; i < n; i += 256) s += partials[i];
    red[threadIdx.x] = s;
    __syncthreads();
    for (int k = 128; k >= 1; k >>= 1) {
        if ((int)threadIdx.x < k) red[threadIdx.x] += red[threadIdx.x + k];
        __syncthreads();
    }
    if (threadIdx.x == 0) out[0] = -red[0] / (float)NB;
}

extern "C" void kernel_launch(void* const* d_in, const int* in_sizes, int n_in,
                              void* d_out, int out_size, void* d_ws, size_t ws_size,
                              hipStream_t stream) {
    const float* X = (const float*)d_in[0];
    const int*   Y = (const int*)d_in[1];
    const float* P = (const float*)d_in[2];
    float* out = (float*)d_out;
    float* partials = (float*)d_ws;   // 256 floats

    crf_fused<<<NB / NIPB, 512, 0, stream>>>(X, Y, P, partials);
    crf_reduce2<<<1, 256, 0, stream>>>(partials, out, NB / NIPB);
}

// Round 11
// 74.672 us; speedup vs baseline: 1.8542x; 1.8542x over previous
//
#include <hip/hip_runtime.h>
#include <hip/hip_fp16.h>
#include <hip/hip_bf16.h>

#define NL 26
#define ND 128
#define NT 64
#define NB 8192
#define NIPB 32   // items per block
#define ITP 34    // padded item stride (bank-conflict-free: 17 banks step)

typedef __attribute__((ext_vector_type(8))) short bf16x8;
typedef __attribute__((ext_vector_type(4))) float f32x4;

__device__ __forceinline__ uint32_t pk_bf16(float lo, float hi) {
    uint32_t r;
    asm("v_cvt_pk_bf16_f32 %0, %1, %2" : "=v"(r) : "v"(lo), "v"(hi));
    return r;
}

// ---------------------------------------------------------------------------
// Producer/consumer fused kernel. Block = 512 thr (8 waves), 32 items,
// grid = 256 = 1 block/CU (LDS ~145 KB pins it).
//  Waves 1-7 (producers): emission GEMM slab-by-slab (slab = 16 t), items
//    split 5/5/5/5/4/4/4; exp(em)/16 fp16 -> emT[t][label][item] (item dim
//    padded to 34 -> conflict-free ds_write); per-item gold chunk; per-slab
//    ready-flag (count 7). X double-buffer uses COMPILE-TIME-NAMED arrays
//    (round-9/10 regression: runtime-selected buffer -> scratch, rule #20).
//  Wave 0 (consumer): two interleaved 16-item MFMA-DP chains per slab.
// DP arithmetic identical to rounds 8-10 (absmax ~3 expected).
// ---------------------------------------------------------------------------
__global__ __launch_bounds__(512, 2) void crf_fused(
    const float* __restrict__ X, const int* __restrict__ Y,
    const float* __restrict__ P, float* __restrict__ partials)
{
    __shared__ float TrS[NL * NL];                    // 2704 B
    __shared__ __half emT[NT][32][ITP];               // 139264 B
    __shared__ alignas(16) uint32_t pScr[2][16][20];  // 2560 B
    __shared__ float goldS[NIPB];                     // 128 B
    __shared__ int ready[4];

    const int tid = threadIdx.x;
    if (tid < 4) ready[tid] = 0;
    if (tid < NIPB) goldS[tid] = 0.f;
    for (int k = tid; k < NL * NL; k += 512) TrS[k] = P[NL * ND + k];
    __syncthreads();

    const int warp = tid >> 6;   // 0..7
    const int lane = tid & 63;
    const int r16  = lane & 15;
    const int kq   = lane >> 4;
    const int item0 = blockIdx.x * NIPB;

    if (warp > 0) {
        // ================= producers (waves 1..7) =================
        bf16x8 Bf[2][4];
        #pragma unroll
        for (int h = 0; h < 2; ++h) {
            int n = r16 + 16 * h;
            #pragma unroll
            for (int kb = 0; kb < 4; ++kb) {
                float w[8];
                if (n < NL) {
                    const float4* wp = reinterpret_cast<const float4*>(P + n * ND + kb * 32 + kq * 8);
                    float4 w0 = wp[0], w1 = wp[1];
                    w[0]=w0.x; w[1]=w0.y; w[2]=w0.z; w[3]=w0.w;
                    w[4]=w1.x; w[5]=w1.y; w[6]=w1.z; w[7]=w1.w;
                } else {
                    #pragma unroll
                    for (int jj = 0; jj < 8; ++jj) w[jj] = 0.f;
                }
                union { uint32_t u[4]; bf16x8 v; } pk;
                pk.u[0] = pk_bf16(w[0], w[1]); pk.u[1] = pk_bf16(w[2], w[3]);
                pk.u[2] = pk_bf16(w[4], w[5]); pk.u[3] = pk_bf16(w[6], w[7]);
                Bf[h][kb] = pk.v;
            }
        }

        const float4* X4 = reinterpret_cast<const float4*>(X);
        const int ibeg = (warp <= 4) ? (warp - 1) * 5 : 20 + (warp - 5) * 4;
        const int cnt  = (warp <= 4) ? 5 : 4;
        const int ntile = 4 * cnt;   // 20 or 16, always even

        auto tile_load = [&](int k, int s, float4 (*xa)[2]) {
            size_t row  = (size_t)(item0 + ibeg + k) * NT + s * 16 + r16;
            size_t base = row * 32 + kq * 2;
            #pragma unroll
            for (int kb = 0; kb < 4; ++kb) {
                xa[kb][0] = X4[base + kb * 8];
                xa[kb][1] = X4[base + kb * 8 + 1];
            }
        };
        auto tile_comp = [&](int k, int s, float4 (*xa)[2]) {
            int it = ibeg + k;
            f32x4 acc0 = {0.f,0.f,0.f,0.f}, acc1 = {0.f,0.f,0.f,0.f};
            #pragma unroll
            for (int kb = 0; kb < 4; ++kb) {
                union { uint32_t u[4]; bf16x8 v; } A;
                A.u[0] = pk_bf16(xa[kb][0].x, xa[kb][0].y);
                A.u[1] = pk_bf16(xa[kb][0].z, xa[kb][0].w);
                A.u[2] = pk_bf16(xa[kb][1].x, xa[kb][1].y);
                A.u[3] = pk_bf16(xa[kb][1].z, xa[kb][1].w);
                acc0 = __builtin_amdgcn_mfma_f32_16x16x32_bf16(A.v, Bf[0][kb], acc0, 0, 0, 0);
                acc1 = __builtin_amdgcn_mfma_f32_16x16x32_bf16(A.v, Bf[1][kb], acc1, 0, 0, 0);
            }
            // D layout: col = lane&15 = label, row = kq*4+q = t-offset  [m89]
            #pragma unroll
            for (int q = 0; q < 4; ++q) {
                int t = s * 16 + kq * 4 + q;
                emT[t][r16][it]      = __float2half(__expf(acc0[q]) * 0.0625f);
                emT[t][r16 + 16][it] = __float2half(__expf(acc1[q]) * 0.0625f);
            }
            // gold chunk for (it, slab s): lanes 0..15 cover the 16 t's
            if (lane < 16) {
                const int* yrow = Y + (size_t)(item0 + it) * NT;
                int tg = s * 16 + lane;
                int yt = yrow[tg];
                float g = __logf(__half2float(emT[tg][yt][it]));
                if (tg < NT - 1) g += TrS[yt * NL + yrow[tg + 1]];
                #pragma unroll
                for (int mk = 8; mk >= 1; mk >>= 1) g += __shfl_xor(g, mk);
                if (lane == 0) goldS[it] += g;
            }
            if (k == cnt - 1) {           // slab s finished by this wave
                __threadfence_block();
                if (lane == 0) atomicAdd(&ready[s], 1);
            }
        };

        // compile-time-named double buffers (rule #20: no runtime select!)
        float4 xaA[4][2], xaB[4][2];
        int kc = 0, sc = 0;               // compute cursor
        tile_load(0, 0, xaA);
        #pragma unroll 1
        for (int li = 0; li < ntile; li += 2) {
            int kn = kc + 1, sn = sc;
            if (kn == cnt) { kn = 0; ++sn; }
            if (sn < 4) tile_load(kn, sn, xaB);
            tile_comp(kc, sc, xaA);
            kc = kn; sc = sn;

            kn = kc + 1; sn = sc;
            if (kn == cnt) { kn = 0; ++sn; }
            if (sn < 4) tile_load(kn, sn, xaA);
            tile_comp(kc, sc, xaB);
            kc = kn; sc = sn;
        }
        return;
    }

    // ================= consumer (wave 0) =================
    // E fragments (B-operand), k-permuted: k-slot 2s -> label s, 2s+1 -> s+16
    bf16x8 Ef[2];
    #pragma unroll
    for (int h = 0; h < 2; ++h) {
        int n = r16 + 16 * h;
        union { uint32_t u[4]; bf16x8 v; } c;
        #pragma unroll
        for (int w = 0; w < 4; ++w) {
            int sl = kq * 4 + w;
            float lo = (n < NL) ? __expf(TrS[sl * NL + n]) : 0.f;
            float hi = (n < NL && sl + 16 < NL) ? __expf(TrS[(sl + 16) * NL + n]) : 0.f;
            c.u[w] = pk_bf16(lo, hi);
        }
        Ef[h] = c.v;
    }

    bf16x8 pfA, pfB;
    float M[2][4] = {{0.f,0.f,0.f,0.f},{0.f,0.f,0.f,0.f}};
    float pn0[2][4], pn1[2][4];
    const f32x4 zacc = {0.f, 0.f, 0.f, 0.f};

    #pragma unroll 1
    for (int s = 0; s < 4; ++s) {
        volatile int* rp = (volatile int*)&ready[s];
        while (*rp < 7) __builtin_amdgcn_s_sleep(8);
        __threadfence_block();

        int t = s * 16;
        if (s == 0) {
            union { uint32_t u[4]; bf16x8 v; } c;
            #pragma unroll
            for (int w = 0; w < 4; ++w) {
                int sl = kq * 4 + w;
                float lo = __half2float(emT[0][sl][r16]);
                float hi = (sl + 16 < NL) ? __half2float(emT[0][sl + 16][r16]) : 0.f;
                c.u[w] = pk_bf16(lo, hi);
            }
            pfA = c.v;
            #pragma unroll
            for (int w = 0; w < 4; ++w) {
                int sl = kq * 4 + w;
                float lo = __half2float(emT[0][sl][16 + r16]);
                float hi = (sl + 16 < NL) ? __half2float(emT[0][sl + 16][16 + r16]) : 0.f;
                c.u[w] = pk_bf16(lo, hi);
            }
            pfB = c.v;
            t = 1;
        }
        const int tend = s * 16 + 16;
        #pragma unroll 1
        for (; t < tend; ++t) {
            f32x4 dA0 = __builtin_amdgcn_mfma_f32_16x16x32_bf16(pfA, Ef[0], zacc, 0, 0, 0);
            f32x4 dA1 = __builtin_amdgcn_mfma_f32_16x16x32_bf16(pfA, Ef[1], zacc, 0, 0, 0);
            f32x4 dB0 = __builtin_amdgcn_mfma_f32_16x16x32_bf16(pfB, Ef[0], zacc, 0, 0, 0);
            f32x4 dB1 = __builtin_amdgcn_mfma_f32_16x16x32_bf16(pfB, Ef[1], zacc, 0, 0, 0);
            #pragma unroll
            for (int g = 0; g < 2; ++g) {
                const f32x4& d0 = g ? dB0 : dA0;
                const f32x4& d1 = g ? dB1 : dA1;
                const __half2* pe0p = reinterpret_cast<const __half2*>(&emT[t][r16][g * 16 + kq * 4]);
                const __half2* pe1p = reinterpret_cast<const __half2*>(&emT[t][r16 + 16][g * 16 + kq * 4]);
                __half2 pe0a = pe0p[0], pe0b = pe0p[1];
                __half2 pe1a = pe1p[0], pe1b = pe1p[1];
                pn0[g][0] = d0[0] * __low2float(pe0a);  pn0[g][1] = d0[1] * __high2float(pe0a);
                pn0[g][2] = d0[2] * __low2float(pe0b);  pn0[g][3] = d0[3] * __high2float(pe0b);
                pn1[g][0] = d1[0] * __low2float(pe1a);  pn1[g][1] = d1[1] * __high2float(pe1a);
                pn1[g][2] = d1[2] * __low2float(pe1b);  pn1[g][3] = d1[3] * __high2float(pe1b);

                if ((t & 3) == 0) {                    // renorm every 4 steps
                    #pragma unroll
                    for (int q = 0; q < 4; ++q) {
                        float m = fmaxf(pn0[g][q], pn1[g][q]);
                        m = fmaxf(m, __shfl_xor(m, 1));
                        m = fmaxf(m, __shfl_xor(m, 2));
                        m = fmaxf(m, __shfl_xor(m, 4));
                        m = fmaxf(m, __shfl_xor(m, 8));
                        float r = __builtin_amdgcn_rcpf(m);
                        pn0[g][q] *= r; pn1[g][q] *= r;
                        M[g][q] += __logf(m);
                    }
                }
                #pragma unroll
                for (int q = 0; q < 4; ++q)
                    pScr[g][kq * 4 + q][r16] = pk_bf16(pn0[g][q], pn1[g][q]);
            }
            uint4 pwA = *reinterpret_cast<const uint4*>(&pScr[0][r16][kq * 4]);
            uint4 pwB = *reinterpret_cast<const uint4*>(&pScr[1][r16][kq * 4]);
            union { uint4 u; bf16x8 v; } pc;
            pc.u = pwA; pfA = pc.v;
            pc.u = pwB; pfB = pc.v;
        }
    }

    // ---- epilogue: per-item logZ, combine with producer-written gold ----
    float tot = 0.f;
    #pragma unroll
    for (int g = 0; g < 2; ++g) {
        #pragma unroll
        for (int q = 0; q < 4; ++q) {
            float ssum = pn0[g][q] + pn1[g][q];
            ssum += __shfl_xor(ssum, 1);
            ssum += __shfl_xor(ssum, 2);
            ssum += __shfl_xor(ssum, 4);
            ssum += __shfl_xor(ssum, 8);
            float logZ = M[g][q] + __logf(ssum);
            tot += goldS[g * 16 + kq * 4 + q] - logZ;   // 1/16 scales cancel
        }
    }
    tot += __shfl_xor(tot, 16);
    tot += __shfl_xor(tot, 32);
    if (lane == 0) partials[blockIdx.x] = tot;
}

__global__ void crf_reduce2(const float* __restrict__ partials,
                            float* __restrict__ out, int n) {
    __shared__ float red[256];
    float s = 0.f;
    for (int i = threadIdx.x; i < n; i += 256) s += partials[i];
    red[threadIdx.x] = s;
    __syncthreads();
    for (int k = 128; k >= 1; k >>= 1) {
        if ((int)threadIdx.x < k) red[threadIdx.x] += red[threadIdx.x + k];
        __syncthreads();
    }
    if (threadIdx.x == 0) out[0] = -red[0] / (float)NB;
}

extern "C" void kernel_launch(void* const* d_in, const int* in_sizes, int n_in,
                              void* d_out, int out_size, void* d_ws, size_t ws_size,
                              hipStream_t stream) {
    const float* X = (const float*)d_in[0];
    const int*   Y = (const int*)d_in[1];
    const float* P = (const float*)d_in[2];
    float* out = (float*)d_out;
    float* partials = (float*)d_ws;   // 256 floats

    crf_fused<<<NB / NIPB, 512, 0, stream>>>(X, Y, P, partials);
    crf_reduce2<<<1, 256, 0, stream>>>(partials, out, NB / NIPB);
}